// Round 17
// baseline (91.263 us; speedup 1.0000x reference)
//
#include <hip/hip_runtime.h>
#include <math.h>

// Problem constants (match reference)
#define T_ 16
#define C_ 4
#define S_ 256
static constexpr float DT      = 0.05f;
static constexpr float JITTER  = 1e-5f;
static constexpr float CLIPV   = 1e4f;

typedef float f32x4 __attribute__((ext_vector_type(4)));

// Output layout (floats, concatenated in return order)
static constexpr int TR_SIZE     = T_ * (C_ * S_) * (C_ * S_);   // 16,777,216
static constexpr int DRIFT_OFF   = TR_SIZE;                       // [T,C,C,2] = 512
static constexpr int DISP_OFF    = DRIFT_OFF + T_ * C_ * C_ * 2;  // [T,C,C,2,2] = 1024
static constexpr int SCALES_OFF  = DISP_OFF + T_ * C_ * C_ * 4;   // [C,C] = 16
static constexpr int MIX_OFF     = SCALES_OFF + C_ * C_;          // 1

__device__ __forceinline__ float sanv(float x) {
    if (isnan(x)) return 0.f;
    return fminf(fmaxf(x, -CLIPV), CLIPV);
}

// ---------------- Fused kernel: prep-in-block + one wave per row -----------
// Block = 4 rows r = blockIdx*4+wave = (t,i,a); t,i are block-uniform
// (blockIdx*4+3 never crosses an a=256 boundary). Threads 0..3 compute the
// 4 (t,i,j) records (identical op sequence to the old prep_kernel ->
// bit-identical results), stash them in LDS; one barrier; all waves read
// broadcast-style. First block of each panel (blockIdx&63==0) writes the
// small drift/disp/scales outputs; block 0 writes mix. ONE kernel launch,
// no ws global round-trip (r15 post-mortem: nt-store A/B was null; the
// remaining structural lever is launch count + prep serialization).
__global__ __launch_bounds__(256)
void fused_kernel(const float* __restrict__ means,
                  const float* __restrict__ covs,
                  const float* __restrict__ site,
                  const float* __restrict__ bsr,
                  const float* __restrict__ mixlogit,
                  float* __restrict__ out) {
    __shared__ float rec[4][8];   // [j]: i00,i01,i11,h,dx,dy,sc,pad
    __shared__ float smix;
    int tid  = threadIdx.x;
    int lane = tid & 63;
    int r0 = blockIdx.x << 2;
    int t = r0 >> 10;             // block-uniform
    int i = (r0 >> 8) & 3;        // block-uniform

    if (tid < 4) {
        int j = tid;
        int bl = (t * C_ + i) * C_ + j;

        // sanitized means -> drift (same ops as old prep_kernel)
        float mix_ = sanv(means[(t * C_ + i) * 2 + 0]);
        float miy  = sanv(means[(t * C_ + i) * 2 + 1]);
        float mjx  = sanv(means[(t * C_ + j) * 2 + 0]);
        float mjy  = sanv(means[(t * C_ + j) * 2 + 1]);
        float dx = sanv(DT * (mix_ - mjx));
        float dy = sanv(DT * (miy - mjy));

        // sanitized+symmetrized covariances
        const float* ci = covs + (t * C_ + i) * 4;
        const float* cj = covs + (t * C_ + j) * 4;
        float ci00 = sanv(ci[0]), ci01 = 0.5f * (sanv(ci[1]) + sanv(ci[2])), ci11 = sanv(ci[3]);
        float cj00 = sanv(cj[0]), cj01 = 0.5f * (sanv(cj[1]) + sanv(cj[2])), cj11 = sanv(cj[3]);

        const float k2 = 2.0f * DT * DT;  // 0.005
        float a = sanv(1.0f + k2 * (ci00 + cj00) + JITTER);
        float b = sanv(        k2 * (ci01 + cj01));
        float c = sanv(1.0f + k2 * (ci11 + cj11) + JITTER);

        // _stable_inv_logdet
        float ds = fmaxf(0.5f * (fabsf(a) + fabsf(c)), 1.0f);
        float ra = 0.f, rb = 0.f, rc = 0.f, det0 = 1.f;
        bool found = false;
        float jit = 1e-5f;
        #pragma unroll
        for (int k = 0; k < 8; ++k) {
            float ja = sanv(a + jit * ds);
            float jb = sanv(b);
            float jc = sanv(c + jit * ds);
            float det = ja * jc - jb * jb;
            if (!found && ja > 0.f && det > 0.f) {
                found = true; ra = ja; rb = jb; rc = jc; det0 = det;
            }
            jit *= 10.f;
        }

        float i00, i01, i11, ld, o00, o01, o11;
        if (found) {
            i00 = sanv(rc / det0);
            i01 = sanv(-rb / det0);
            i11 = sanv(ra / det0);
            ld = logf(det0);
            if (isnan(ld)) ld = 0.f;
            else if (isinf(ld)) ld = (ld > 0.f) ? 20.f : -20.f;
            o00 = ra; o01 = rb; o11 = rc;
        } else {
            float jf = 1e3f;
            float sd0 = fmaxf(fabsf(a), jf * ds + 1e-4f);
            float sd1 = fmaxf(fabsf(c), jf * ds + 1e-4f);
            o00 = sanv(sd0 + jf * ds); o11 = sanv(sd1 + jf * ds); o01 = 0.f;
            float dg0 = fmaxf(o00, 1e-6f), dg1 = fmaxf(o11, 1e-6f);
            i00 = sanv(1.f / dg0); i11 = sanv(1.f / dg1); i01 = 0.f;
            ld = logf(dg0) + logf(dg1);
            if (isnan(ld)) ld = 0.f;
            else if (isinf(ld)) ld = (ld > 0.f) ? 20.f : -20.f;
        }

        // scales: softplus(bsr) + 0.01
        float x = bsr[i * 4 + j];
        float sc = fmaxf(x, 0.f) + log1pf(expf(-fabsf(x))) + 0.01f;

        rec[j][0] = i00; rec[j][1] = i01; rec[j][2] = i11; rec[j][3] = -0.5f * ld;
        rec[j][4] = dx;  rec[j][5] = dy;  rec[j][6] = sc;

        // small outputs: exactly one block per (t,i) panel writes them
        if ((blockIdx.x & 63) == 0) {
            out[DRIFT_OFF + bl * 2 + 0] = dx;
            out[DRIFT_OFF + bl * 2 + 1] = dy;
            out[DISP_OFF + bl * 4 + 0] = o00;
            out[DISP_OFF + bl * 4 + 1] = o01;
            out[DISP_OFF + bl * 4 + 2] = o01;
            out[DISP_OFF + bl * 4 + 3] = o11;
            if (t == 0) out[SCALES_OFF + i * 4 + j] = sc;
        }
    }
    if (tid == 4) {   // lane 4, same wave as the record threads: no extra divergence cost
        float lg = mixlogit[0];
        float mxv = 1.f / (1.f + expf(-lg));
        smix = mxv;
        if (blockIdx.x == 0) out[MIX_OFF] = mxv;
    }
    __syncthreads();

    int r = __builtin_amdgcn_readfirstlane(r0 | (tid >> 6));
    int a = r & 255;

    // lane's 4 sites: b = 4*lane .. 4*lane+3 (128 f32x4 total; max idx 127)
    const f32x4* s4 = (const f32x4*)site;
    f32x4 p0 = s4[2 * lane];
    f32x4 p1 = s4[2 * lane + 1];
    float2 sa = ((const float2*)site)[a];        // wave-uniform
    float mx = smix;

    float bx[4] = {p0.x, p0.z, p1.x, p1.z};
    float by[4] = {p0.y, p0.w, p1.y, p1.w};

    float v[4][4];
    float local = 0.f;
    #pragma unroll
    for (int k = 0; k < 4; ++k) {                // k = j-block; LDS broadcast reads
        float i00 = rec[k][0], i01 = rec[k][1], i11 = rec[k][2], h = rec[k][3];
        float dx = rec[k][4],  dy = rec[k][5],  sc = rec[k][6];
        float ox = sa.x - dx, oy = sa.y - dy;
        #pragma unroll
        for (int s = 0; s < 4; ++s) {
            float cx = ox - bx[s], cy = oy - by[s];
            float u = i00 * cx + i01 * cy;
            float z = i01 * cx + i11 * cy;
            float q = cx * u + cy * z;
            q = fminf(fmaxf(q, 0.f), 60.f);                 // binding clip: keep
            float e = fminf(fmaxf(h - q, -60.f), 20.f);     // binding clip: keep
            float val = sc * __expf(e);
            v[k][s] = val;
            local += val;
        }
    }

    // 64-lane butterfly all-reduce (no barrier)
    #pragma unroll
    for (int m = 1; m < 64; m <<= 1) local += __shfl_xor(local, m, 64);
    float s1 = local;

    // uniform epilogue with v_rcp_f32 (rel err ~1e-7 << absmax headroom)
    float d1 = fmaxf(s1, JITTER);
    float r1 = __builtin_amdgcn_rcpf(d1);
    float s2 = s1 * r1;
    float d2 = fmaxf(s2, JITTER);
    float r2 = __builtin_amdgcn_rcpf(d2);
    float sum_t2 = s2 * r2;
    float omx = 1.f - mx;
    float s3 = omx * sum_t2 + mx;
    float d3 = fmaxf(s3, JITTER);
    float r3 = __builtin_amdgcn_rcpf(d3);
    float scale = omx * r1 * r2 * r3;
    float diag  = mx * r3;

    size_t base = ((size_t)t << 20) + (size_t)(i * S_ + a) * 1024;
    f32x4* dst = (f32x4*)(out + base);
    #pragma unroll
    for (int k = 0; k < 4; ++k) {
        f32x4 o;
        o.x = v[k][0] * scale; o.y = v[k][1] * scale;
        o.z = v[k][2] * scale; o.w = v[k][3] * scale;
        // diagonal of the (i,i) block: k==i, lane a>>2, slot a&3
        if (k == i && lane == (a >> 2)) {
            int sl = a & 3;
            if      (sl == 0) o.x += diag;
            else if (sl == 1) o.y += diag;
            else if (sl == 2) o.z += diag;
            else              o.w += diag;
        }
        dst[(k << 6) + lane] = o;
    }
}

extern "C" void kernel_launch(void* const* d_in, const int* in_sizes, int n_in,
                              void* d_out, int out_size, void* d_ws, size_t ws_size,
                              hipStream_t stream) {
    const float* means    = (const float*)d_in[0];
    const float* covs     = (const float*)d_in[1];
    const float* site     = (const float*)d_in[2];
    const float* bsr      = (const float*)d_in[3];
    const float* mixlogit = (const float*)d_in[4];
    float* out = (float*)d_out;

    fused_kernel<<<(T_ * C_ * S_) / 4, 256, 0, stream>>>(means, covs, site, bsr, mixlogit, out);
}